// Round 1
// 203.663 us; speedup vs baseline: 1.1595x; 1.1595x over previous
//
#include <hip/hip_runtime.h>

// PixelPropagationModule  out = gamma * (softmax(qk^T) @ v^T)^T + x
// B=8, C=256, CI=64, N=3136 (56x56), fp32 in/out.
// R8: attn latency-pipeline rewrite.
//     - Dedup: wave = 16q x 256ch (O[16]), block = 64q, grid = B*49*JS = 1568.
//       QK MFMA + exp no longer duplicated across ch-half waves.
//     - Double-buffered V LDS (2 x [256][40] ushort = 40960 B), ONE
//       __syncthreads per step: V prefetch issued at step start, committed
//       after PV -> full-step latency window; K prefetched one step ahead
//       into alternating named reg sets (static parity, 2-step unrolled
//       loop) so QK never waits on vmcnt.
//     - XCD swizzle: bx&7 = batch -> per-XCD working set (q/k/vt of one
//       batch ~2.4MB) fits the 4MB XCD L2.
//     - s_setprio(1) around the 16-MFMA PV cluster.
//     pre/proj/reduce unchanged from R7.

constexpr int B_  = 8;
constexpr int C_  = 256;
constexpr int CI_ = 64;
constexpr int N_  = 3136;
constexpr int JS  = 4;        // attn j-split
constexpr int JT  = 32;       // attn j per step
constexpr int VSP = 40;       // V LDS row pitch (ushorts) = 80 B
constexpr int PN  = 64;       // proj pixel tile
constexpr int XSP = C_ + 8;   // proj LDS row pitch

typedef __attribute__((ext_vector_type(8))) short short8;   // 8 bf16 (4 VGPR)
typedef __attribute__((ext_vector_type(4))) float f32x4;

static __device__ inline ushort f2b(float f) {               // fp32 -> bf16 (RNE)
    unsigned u = __float_as_uint(f);
    return (ushort)((u + 0x7fffu + ((u >> 16) & 1u)) >> 16);
}
static __device__ inline float b2f(ushort h) {
    return __uint_as_float(((unsigned)h) << 16);
}

// blocks [0, B_*196): x[B][C][N] f32 -> xT[B][N][C] bf16 (LDS transpose)
// blocks [B_*196, +256): Wq/Wk -> wqk[128][256], Wv -> wv[256][256] bf16
__global__ __launch_bounds__(256)
void pre_kernel(const float* __restrict__ x,
                const float* __restrict__ Wq, const float* __restrict__ Wk,
                const float* __restrict__ Wv,
                ushort* __restrict__ xT, ushort* __restrict__ wqk, ushort* __restrict__ wv)
{
    __shared__ float ts[64][65];
    const int bx  = blockIdx.x;
    const int tid = threadIdx.x;

    if (bx >= B_ * 196) {                            // weight convert
        int i = (bx - B_ * 196) * 256 + tid;
        if (i < 16384)      wqk[i] = f2b(Wq[i]);
        else if (i < 32768) wqk[i] = f2b(Wk[i - 16384]);
        wv[i] = f2b(Wv[i]);
        return;
    }

    const int b  = bx / 196;
    const int rm = bx % 196;
    const int n0 = (rm >> 2) * 64;
    const int c0 = (rm & 3) * 64;

    const float* src = x + ((size_t)b * C_ + c0) * N_ + n0;
    #pragma unroll
    for (int rep = 0; rep < 16; rep++) {             // 4096 floats in
        int e = rep * 256 + tid;
        int c = e >> 6, n = e & 63;
        ts[c][n] = src[(size_t)c * N_ + n];
    }
    __syncthreads();
    ushort* dst = xT + ((size_t)b * N_ + n0) * C_ + c0;
    #pragma unroll
    for (int rep = 0; rep < 8; rep++) {              // 2048 ushort2 out
        int e = rep * 256 + tid;
        int n = e >> 5, c2 = (e & 31) * 2;
        ushort2 o;
        o.x = f2b(ts[c2][n]);
        o.y = f2b(ts[c2 + 1][n]);
        *(ushort2*)(dst + (size_t)n * C_ + c2) = o;
    }
}

__global__ __launch_bounds__(256)
void proj_kernel(const ushort* __restrict__ xT, const ushort* __restrict__ wqk,
                 const ushort* __restrict__ wv,
                 const float* __restrict__ bq, const float* __restrict__ bk,
                 const float* __restrict__ bv,
                 ushort* __restrict__ qb, ushort* __restrict__ kb, ushort* __restrict__ vt)
{
    __shared__ ushort xs[PN][XSP];        // 33792 B
    const int b   = blockIdx.x / 49;
    const int n0  = (blockIdx.x % 49) * PN;
    const int tid = threadIdx.x;
    const int w    = tid >> 6;
    const int lane = tid & 63;
    const int m16  = lane & 15;
    const int quad = lane >> 4;

    // stage xT tile [64 pixels][256 c] bf16
    {
        const ushort* src = xT + ((size_t)b * N_ + n0) * C_;
        #pragma unroll
        for (int rep = 0; rep < 8; rep++) {
            int e = rep * 256 + tid;
            int row = e >> 5, ch = (e & 31) * 8;
            *(short8*)&xs[row][ch] = *(const short8*)(src + (size_t)row * C_ + ch);
        }
    }
    __syncthreads();

    // ---- QK GEMM: C[o][pixel]; waves 0,1 -> Q halves, 2,3 -> K halves ----
    {
        f32x4 acc[2][4];
        #pragma unroll
        for (int mt = 0; mt < 2; mt++)
            #pragma unroll
            for (int nt = 0; nt < 4; nt++) acc[mt][nt] = (f32x4){0.f, 0.f, 0.f, 0.f};

        #pragma unroll
        for (int kk = 0; kk < 8; kk++) {
            short8 af[2];
            #pragma unroll
            for (int mt = 0; mt < 2; mt++)   // A[m=o][k=c] = wqk row (L2-hot)
                af[mt] = *(const short8*)(wqk + (size_t)(w * 32 + mt * 16 + m16) * C_ + kk * 32 + quad * 8);
            #pragma unroll
            for (int nt = 0; nt < 4; nt++) {
                short8 bf = *(const short8*)&xs[nt * 16 + m16][kk * 32 + quad * 8];  // B[k=c][n=pix]
                #pragma unroll
                for (int mt = 0; mt < 2; mt++)
                    acc[mt][nt] = __builtin_amdgcn_mfma_f32_16x16x32_bf16(af[mt], bf, acc[mt][nt], 0, 0, 0);
            }
        }
        const float* bias = (w < 2) ? bq : bk;
        ushort* dst = (w < 2) ? qb : kb;
        const int obase = (w & 1) * 32;
        #pragma unroll
        for (int mt = 0; mt < 2; mt++) {
            f32x4 bs = *(const f32x4*)(bias + obase + mt * 16 + quad * 4);
            #pragma unroll
            for (int nt = 0; nt < 4; nt++) {
                ushort4 pk;
                pk.x = f2b(acc[mt][nt][0] + bs[0]);
                pk.y = f2b(acc[mt][nt][1] + bs[1]);
                pk.z = f2b(acc[mt][nt][2] + bs[2]);
                pk.w = f2b(acc[mt][nt][3] + bs[3]);
                *(ushort4*)(dst + ((size_t)b * N_ + n0 + nt * 16 + m16) * CI_ + obase + mt * 16 + quad * 4) = pk;
            }
        }
    }

    // ---- V GEMM: C[pixel][o]; wave w -> channels w*64..w*64+63 ----
    {
        f32x4 vacc[4][4];
        #pragma unroll
        for (int mt = 0; mt < 4; mt++)
            #pragma unroll
            for (int nt = 0; nt < 4; nt++) vacc[mt][nt] = (f32x4){0.f, 0.f, 0.f, 0.f};

        #pragma unroll
        for (int kk = 0; kk < 8; kk++) {
            short8 af[4];
            #pragma unroll
            for (int mt = 0; mt < 4; mt++)   // A[m=pix][k=c] from LDS
                af[mt] = *(const short8*)&xs[mt * 16 + m16][kk * 32 + quad * 8];
            #pragma unroll
            for (int nt = 0; nt < 4; nt++) {
                short8 bf = *(const short8*)(wv + (size_t)(w * 64 + nt * 16 + m16) * C_ + kk * 32 + quad * 8);
                #pragma unroll
                for (int mt = 0; mt < 4; mt++)
                    vacc[mt][nt] = __builtin_amdgcn_mfma_f32_16x16x32_bf16(af[mt], bf, vacc[mt][nt], 0, 0, 0);
            }
        }
        #pragma unroll
        for (int nt = 0; nt < 4; nt++) {
            int c = w * 64 + nt * 16 + m16;
            float bvc = bv[c];
            #pragma unroll
            for (int mt = 0; mt < 4; mt++) {
                ushort4 pk;
                pk.x = f2b(vacc[mt][nt][0] + bvc);
                pk.y = f2b(vacc[mt][nt][1] + bvc);
                pk.z = f2b(vacc[mt][nt][2] + bvc);
                pk.w = f2b(vacc[mt][nt][3] + bvc);
                *(ushort4*)(vt + ((size_t)b * C_ + c) * N_ + n0 + mt * 16 + quad * 4) = pk;
            }
        }
    }
}

// grid B_*49*JS = 1568. XCD swizzle: b = bx&7 (one batch per XCD -> q/k/vt
// working set ~2.4MB fits 4MB XCD L2); rem = bx>>3: t = rem>>2 (64q tile),
// js = rem&3. Wave w: queries t*64+w*16, ALL 256 channels (16 ct) -> no
// QK/exp duplication. S^T = K*Q^T -> exp in-register -> A-frag pa.
// V tile [256][32] double-buffered in LDS with the PV k-perm pre-applied:
//   global j-seg seg*8 -> pos p0=(seg&1)*16+(seg>>1)*4 and p0+8
// so B-frag = ONE ds_read_b128 at vs[buf][c][quad*8]. One barrier/step:
// V prefetch issued at step start, committed after PV; K prefetched one
// step ahead into alternating named reg sets (static parity via 2-step
// unrolled loop). Partial O bf16 [b][js][c][i], partial l fp32.
__global__ __launch_bounds__(256, 3)
void attn_kernel(const ushort* __restrict__ qb, const ushort* __restrict__ kb,
                 const ushort* __restrict__ vt,
                 ushort* __restrict__ op, float* __restrict__ lp)
{
    __shared__ __align__(16) ushort vs[2][C_][VSP];  // 40960 B -> 3 blocks/CU

    const int bx   = blockIdx.x;
    const int b    = bx & 7;            // XCD-local batch
    const int rem  = bx >> 3;           // 0..195
    const int t    = rem >> 2;          // 0..48
    const int js   = rem & 3;
    const int tid  = threadIdx.x;
    const int w    = tid >> 6;
    const int lane = tid & 63;
    const int m16  = lane & 15;
    const int quad = lane >> 4;
    const int i0   = t * 64 + w * 16;

    const int steps = (js == 0) ? 13 : 12;               // 13+12+12+12 = 49
    const int jbase = ((js == 0) ? 0 : (1 + 12 * js)) * JT;

    const ushort* vtb = vt + (size_t)b * C_ * N_;
    const ushort* kbb = kb + (size_t)b * N_ * CI_;

    // Q B-frags (n=i side), loaded once: B[k=o][n=i] = q[i][o]
    short8 qf[2];
    {
        const ushort* qbase = qb + ((size_t)b * N_ + i0 + m16) * CI_;
        qf[0] = *(const short8*)(qbase + quad * 8);
        qf[1] = *(const short8*)(qbase + 32 + quad * 8);
    }

    f32x4 O[16];
    #pragma unroll
    for (int ct = 0; ct < 16; ct++) O[ct] = (f32x4){0.f, 0.f, 0.f, 0.f};
    float lsum = 0.f;

    // staging: thread -> c row (4 thr/row), 16B global segment seg
    const int sc  = tid >> 2;
    const int seg = tid & 3;
    const int p0  = (seg & 1) * 16 + (seg >> 1) * 4;     // permuted dest base

    short8 pr[4];                 // V prefetch regs (single set, 1-step window)
    short8 krA[4], krB[4];        // K prefetch, alternating named sets

    #define PREFETCH(J0)                                                       \
        {                                                                      \
            _Pragma("unroll")                                                  \
            for (int p = 0; p < 4; p++)                                        \
                pr[p] = *(const short8*)(vtb + (size_t)(p * 64 + sc) * N_ + (J0) + seg * 8); \
        }
    #define COMMIT(BUF)                                                        \
        {                                                                      \
            _Pragma("unroll")                                                  \
            for (int p = 0; p < 4; p++) {                                      \
                *(ushort4*)&vs[BUF][p * 64 + sc][p0]     = ((const ushort4*)&pr[p])[0]; \
                *(ushort4*)&vs[BUF][p * 64 + sc][p0 + 8] = ((const ushort4*)&pr[p])[1]; \
            }                                                                  \
        }
    #define KLOAD(J0, KR)                                                      \
        {                                                                      \
            _Pragma("unroll")                                                  \
            for (int h = 0; h < 2; h++) {                                      \
                const ushort* krow = kbb + (size_t)((J0) + h * 16 + m16) * CI_; \
                KR[2 * h]     = *(const short8*)(krow + quad * 8);             \
                KR[2 * h + 1] = *(const short8*)(krow + 32 + quad * 8);        \
            }                                                                  \
        }

    // prologue: tile 0 -> vs[0], K(0) -> krA
    PREFETCH(jbase)
    COMMIT(0)
    KLOAD(jbase, krA)
    __syncthreads();

    // one step: CUR is a literal 0/1 (buffer + reg-set parity), KRC holds
    // this step's K (loaded last step), KRN receives next step's K.
    #define STEP(CUR, KRC, KRN, ST)                                            \
    {                                                                          \
        const int j0_ = jbase + (ST) * JT;                                     \
        const bool more_ = (ST) + 1 < steps;                                   \
        if (more_) { PREFETCH(j0_ + JT) KLOAD(j0_ + JT, KRN) }                 \
        /* ---- S^T = K Q^T, exp in-register -> A-frag pa ---- */              \
        short8 pa;                                                             \
        _Pragma("unroll")                                                      \
        for (int h = 0; h < 2; h++) {                                          \
            f32x4 T = (f32x4){0.f, 0.f, 0.f, 0.f};                             \
            T = __builtin_amdgcn_mfma_f32_16x16x32_bf16(KRC[2 * h],     qf[0], T, 0, 0, 0); \
            T = __builtin_amdgcn_mfma_f32_16x16x32_bf16(KRC[2 * h + 1], qf[1], T, 0, 0, 0); \
            _Pragma("unroll")                                                  \
            for (int r = 0; r < 4; r++) {                                      \
                float pv = __expf(T[r] - 12.0f);   /* static shift */          \
                lsum += pv;                                                    \
                pa[h * 4 + r] = (short)f2b(pv);                                \
            }                                                                  \
        }                                                                      \
        /* ---- PV: O[i][c] += P V over all 256 ch ---- */                     \
        __builtin_amdgcn_s_setprio(1);                                         \
        _Pragma("unroll")                                                      \
        for (int ct = 0; ct < 16; ct++) {                                      \
            short8 vf = *(const short8*)&vs[CUR][ct * 16 + m16][quad * 8];     \
            O[ct] = __builtin_amdgcn_mfma_f32_16x16x32_bf16(pa, vf, O[ct], 0, 0, 0); \
        }                                                                      \
        __builtin_amdgcn_s_setprio(0);                                         \
        if (more_) COMMIT((CUR) ^ 1)                                           \
        __syncthreads();                                                       \
    }

    int st = 0;
    for (; st + 2 <= steps; st += 2) {
        STEP(0, krA, krB, st)
        STEP(1, krB, krA, st + 1)
    }
    if (st < steps)                       // steps==13 tail (even parity)
        STEP(0, krA, krB, st)

    // ---- in-wave l reduction over quads; every wave owns unique 16 q ----
    {
        float v = lsum;
        v += __shfl_xor(v, 16);
        v += __shfl_xor(v, 32);
        if (lane < 16)
            lp[(size_t)(b * JS + js) * N_ + i0 + lane] = v;
    }

    // ---- store bf16 partial O: op[b][js][c][i] ----
    ushort* opb = op + (size_t)(b * JS + js) * C_ * N_;
    #pragma unroll
    for (int ct = 0; ct < 16; ct++) {
        ushort4 pk;
        pk.x = f2b(O[ct][0]);
        pk.y = f2b(O[ct][1]);
        pk.z = f2b(O[ct][2]);
        pk.w = f2b(O[ct][3]);
        *(ushort4*)(opb + (size_t)(ct * 16 + m16) * N_ + i0 + quad * 4) = pk;
    }
    #undef PREFETCH
    #undef COMMIT
    #undef KLOAD
    #undef STEP
}

// grid 6272: thread -> (b, c, 4 consecutive i). out = gamma*Σp/Σl + x
__global__ __launch_bounds__(256)
void reduce_kernel(const ushort* __restrict__ op, const float* __restrict__ lp,
                   const float* __restrict__ x, const float* __restrict__ gamma_p,
                   float* __restrict__ out)
{
    const int g  = blockIdx.x * 256 + threadIdx.x;   // B*C*N/4 total
    const int i4 = g % (N_ / 4);
    const int c  = (g / (N_ / 4)) % C_;
    const int b  = g / ((N_ / 4) * C_);
    const size_t io = (size_t)i4 * 4;
    const float g0 = gamma_p[0];

    f32x4 acc = (f32x4){0.f, 0.f, 0.f, 0.f};
    f32x4 lt  = (f32x4){0.f, 0.f, 0.f, 0.f};
    #pragma unroll
    for (int js = 0; js < JS; js++) {
        ushort4 a = *(const ushort4*)(op + ((size_t)(b * JS + js) * C_ + c) * N_ + io);
        f32x4   l = *(const f32x4*)(lp + (size_t)(b * JS + js) * N_ + io);
        acc[0] += b2f(a.x); acc[1] += b2f(a.y); acc[2] += b2f(a.z); acc[3] += b2f(a.w);
        lt += l;
    }

    const size_t xo = ((size_t)b * C_ + c) * N_ + io;
    f32x4 xv = *(const f32x4*)(x + xo);
    f32x4 ov;
    #pragma unroll
    for (int u = 0; u < 4; u++) ov[u] = acc[u] * (g0 / lt[u]) + xv[u];
    *(f32x4*)(out + xo) = ov;
}

extern "C" void kernel_launch(void* const* d_in, const int* in_sizes, int n_in,
                              void* d_out, int out_size, void* d_ws, size_t ws_size,
                              hipStream_t stream)
{
    const float* x  = (const float*)d_in[0];
    const float* Wq = (const float*)d_in[1];
    const float* bq = (const float*)d_in[2];
    const float* Wk = (const float*)d_in[3];
    const float* bk = (const float*)d_in[4];
    const float* Wv = (const float*)d_in[5];
    const float* bv = (const float*)d_in[6];
    const float* gm = (const float*)d_in[7];
    float* out = (float*)d_out;

    ushort* qb   = (ushort*)d_ws;                    // [B][N][CI]  3.2 MB
    ushort* kb   = qb + (size_t)B_ * N_ * CI_;       // [B][N][CI]  3.2 MB
    ushort* vt   = kb + (size_t)B_ * N_ * CI_;       // [B][C][N]  12.8 MB
    ushort* xT   = vt + (size_t)B_ * C_ * N_;        // [B][N][C]  12.8 MB
    ushort* wqk  = xT + (size_t)B_ * N_ * C_;        // [128][256] 64 KB
    ushort* wv   = wqk + 128 * C_;                   // [256][256] 128 KB
    ushort* op   = wv + 256 * C_;                    // [B][JS][C][N] bf16 51.4 MB
    float*  lpf  = (float*)(op + (size_t)B_ * JS * C_ * N_);  // [B][JS][N] 401 KB

    hipLaunchKernelGGL(pre_kernel, dim3(B_ * 196 + 256), dim3(256), 0, stream,
                       x, Wq, Wk, Wv, xT, wqk, wv);
    hipLaunchKernelGGL(proj_kernel, dim3(B_ * 49), dim3(256), 0, stream,
                       xT, wqk, wv, bq, bk, bv, qb, kb, vt);
    hipLaunchKernelGGL(attn_kernel, dim3(B_ * 49 * JS), dim3(256), 0, stream,
                       qb, kb, vt, op, lpf);
    hipLaunchKernelGGL(reduce_kernel, dim3(B_ * C_ * (N_ / 4) / 256), dim3(256), 0, stream,
                       op, lpf, x, gm, out);
}